// Round 1
// baseline (284.861 us; speedup 1.0000x reference)
//
#include <hip/hip_runtime.h>
#include <hip/hip_bf16.h>
#include <stdint.h>

#define DM   1024
#define DKV  64
#define HEADS 16
#define BATCH 2
#define SEQ  2048
#define BS   (BATCH*SEQ)    // 4096
#define BHD  (BATCH*HEADS)  // 32

typedef __attribute__((ext_vector_type(8))) short bf16x8;
typedef __attribute__((ext_vector_type(4))) short bf16x4;
typedef __attribute__((ext_vector_type(4))) float f32x4;

// ---------- helpers ----------
__device__ inline unsigned fb(float f) { union { float f; unsigned u; } v; v.f = f; return v.u; }

__device__ inline unsigned short bf16_rtn(float f) {
  unsigned u = fb(f);
  unsigned r = u + 0x7fffu + ((u >> 16) & 1u);
  return (unsigned short)(r >> 16);
}
__device__ inline float bf16_to_f(unsigned short h) {
  union { unsigned u; float f; } v; v.u = ((unsigned)h) << 16; return v.f;
}
// split x ≈ hi + lo, |lo| <= 2^-9 |x|, residual ~2^-18
__device__ inline void split_bf16(float x, unsigned short& hi, unsigned short& lo) {
  hi = bf16_rtn(x);
  lo = bf16_rtn(x - bf16_to_f(hi));
}
// pack two fp32 -> two bf16 (round-half-up) in one dword via v_perm_b32
__device__ inline unsigned pack2_bf16(float lo_elem, float hi_elem) {
  return __builtin_amdgcn_perm(fb(hi_elem) + 0x8000u, fb(lo_elem) + 0x8000u, 0x07060302u);
}

__device__ inline float fast_exp2(float x) {
#if __has_builtin(__builtin_amdgcn_exp2f)
  return __builtin_amdgcn_exp2f(x);
#else
  return exp2f(x);
#endif
}

__device__ inline f32x4 mfma16x16x16_bf16(bf16x4 a, bf16x4 b, f32x4 c) {
#if __has_builtin(__builtin_amdgcn_mfma_f32_16x16x16bf16_1k)
  return __builtin_amdgcn_mfma_f32_16x16x16bf16_1k(a, b, c, 0, 0, 0);
#else
  asm volatile("v_mfma_f32_16x16x16_bf16 %0, %1, %2, %0" : "+v"(c) : "v"(a), "v"(b));
  return c;
#endif
}

// stage 16B/lane: async direct-to-LDS (dest = wave-uniform base + lane*16)
__device__ inline void stage16(const unsigned short* g, unsigned short* lds_base, int lane) {
#if __has_builtin(__builtin_amdgcn_global_load_lds)
  __builtin_amdgcn_global_load_lds((__attribute__((address_space(1))) void*)(g),
                                   (__attribute__((address_space(3))) void*)(lds_base),
                                   16, 0, 0);
#else
  *(bf16x8*)(lds_base + lane * 8) = *(const bf16x8*)g;
#endif
}

// XOR-swizzled LDS index for a 64-col bf16 tile (8 chunks of 8 shorts per row)
__device__ inline int swz(int row, int chunk) {
  return row * 64 + (((chunk ^ (row & 7)) & 7) << 3);
}

// ---------- pack kernels ----------
__global__ void cvt_x_split(const float* __restrict__ x,
                            unsigned short* __restrict__ xh, unsigned short* __restrict__ xl) {
  int i = (blockIdx.x * 256 + threadIdx.x) * 8;
  bf16x8 oh, ol;
  #pragma unroll
  for (int j = 0; j < 8; ++j) {
    unsigned short hi, lo;
    split_bf16(x[i + j], hi, lo);
    oh[j] = (short)hi; ol[j] = (short)lo;
  }
  *(bf16x8*)(xh + i) = oh;
  *(bf16x8*)(xl + i) = ol;
}

// WcatT[c'][m] split, c' = p*1024 + h*64 + k  (p: 0=Q,1=K,2=V), from W_p[h][m][k]
__global__ void pack_qkv_split(const float* __restrict__ Wq, const float* __restrict__ Wk,
                               const float* __restrict__ Wv,
                               unsigned short* __restrict__ Wh, unsigned short* __restrict__ Wl) {
  __shared__ float tile[64][65];
  int bid = blockIdx.x;               // p*256 + h*16 + mt
  int p = bid >> 8, h = (bid >> 4) & 15, mt = bid & 15;
  const float* W = (p == 0) ? Wq : (p == 1) ? Wk : Wv;
  const float* src = W + (size_t)h * (DM * DKV);
  int t = threadIdx.x;
  int m0 = mt * 64;
  #pragma unroll
  for (int pass = 0; pass < 16; ++pass) {
    int row = pass * 4 + (t >> 6), col = t & 63;
    tile[row][col] = src[(size_t)(m0 + row) * DKV + col];
  }
  __syncthreads();
  int cbase = p * 1024 + h * 64;
  #pragma unroll
  for (int pass = 0; pass < 16; ++pass) {
    int krow = pass * 4 + (t >> 6), mcol = t & 63;
    unsigned short hi, lo;
    split_bf16(tile[mcol][krow], hi, lo);
    size_t idx = (size_t)(cbase + krow) * DM + m0 + mcol;
    Wh[idx] = hi; Wl[idx] = lo;
  }
}

// WoT[mo][c] = Wo[c][mo], single bf16
__global__ void pack_wo(const float* __restrict__ Wo, unsigned short* __restrict__ WoT) {
  __shared__ float tile[64][65];
  int ib = blockIdx.x >> 4, jb = blockIdx.x & 15;
  int t = threadIdx.x;
  #pragma unroll
  for (int pass = 0; pass < 16; ++pass) {
    int row = pass * 4 + (t >> 6), col = t & 63;
    tile[row][col] = Wo[(size_t)(ib * 64 + row) * DM + jb * 64 + col];
  }
  __syncthreads();
  #pragma unroll
  for (int pass = 0; pass < 16; ++pass) {
    int a = pass * 4 + (t >> 6), b = t & 63;
    WoT[(size_t)(jb * 64 + a) * DM + ib * 64 + b] = bf16_rtn(tile[b][a]);
  }
}

// ---------- gemm_qk: split-precision x@Wqk^T, N=2048, tile 128x128x32 ----------
// grid dim3(16=bn, 32=bm): id%8 = bn%8 -> weight tiles pinned per XCD
__global__ __launch_bounds__(256, 2)
void gemm_qk(const unsigned short* __restrict__ Ah, const unsigned short* __restrict__ Al,
             const unsigned short* __restrict__ Bh, const unsigned short* __restrict__ Bl,
             unsigned short* __restrict__ Qh, unsigned short* __restrict__ Ql,
             unsigned short* __restrict__ Kh, unsigned short* __restrict__ Kl) {
  __shared__ unsigned short AsH[128 * 32], AsL[128 * 32];
  __shared__ unsigned short BsH[128 * 32], BsL[128 * 32];
  const int tid = threadIdx.x;
  const int w = tid >> 6, lane = tid & 63;
  const int quad = lane >> 4, l16 = lane & 15;
  const int wm = w >> 1, wn = w & 1;
  const int bn = blockIdx.x, bm = blockIdx.y;

  f32x4 acc[4][4];
  #pragma unroll
  for (int i = 0; i < 4; ++i)
    #pragma unroll
    for (int j = 0; j < 4; ++j) acc[i][j] = (f32x4){0.f, 0.f, 0.f, 0.f};

  const int r4 = lane >> 2, c4 = lane & 3;
  const size_t offA = (size_t)(bm * 128 + w * 32 + r4) * DM + c4 * 8;
  const size_t offB = (size_t)(bn * 128 + w * 32 + r4) * DM + c4 * 8;
  unsigned short* lAh0 = AsH + (w * 32) * 32;      unsigned short* lAh1 = AsH + (w * 32 + 16) * 32;
  unsigned short* lAl0 = AsL + (w * 32) * 32;      unsigned short* lAl1 = AsL + (w * 32 + 16) * 32;
  unsigned short* lBh0 = BsH + (w * 32) * 32;      unsigned short* lBh1 = BsH + (w * 32 + 16) * 32;
  unsigned short* lBl0 = BsL + (w * 32) * 32;      unsigned short* lBl1 = BsL + (w * 32 + 16) * 32;

  for (int kk = 0; kk < DM / 32; ++kk) {
    stage16(Ah + offA + kk * 32,           lAh0, lane);
    stage16(Ah + offA + kk * 32 + 16 * DM, lAh1, lane);
    stage16(Al + offA + kk * 32,           lAl0, lane);
    stage16(Al + offA + kk * 32 + 16 * DM, lAl1, lane);
    stage16(Bh + offB + kk * 32,           lBh0, lane);
    stage16(Bh + offB + kk * 32 + 16 * DM, lBh1, lane);
    stage16(Bl + offB + kk * 32,           lBl0, lane);
    stage16(Bl + offB + kk * 32 + 16 * DM, lBl1, lane);
    asm volatile("s_waitcnt vmcnt(0)" ::: "memory");
    __syncthreads();
    bf16x8 afh[4], afl[4], bfh[4], bfl[4];
    #pragma unroll
    for (int mt = 0; mt < 4; ++mt) {
      afh[mt] = *(const bf16x8*)(AsH + (wm * 64 + mt * 16 + l16) * 32 + quad * 8);
      afl[mt] = *(const bf16x8*)(AsL + (wm * 64 + mt * 16 + l16) * 32 + quad * 8);
    }
    #pragma unroll
    for (int nt = 0; nt < 4; ++nt) {
      bfh[nt] = *(const bf16x8*)(BsH + (wn * 64 + nt * 16 + l16) * 32 + quad * 8);
      bfl[nt] = *(const bf16x8*)(BsL + (wn * 64 + nt * 16 + l16) * 32 + quad * 8);
    }
    #pragma unroll
    for (int mt = 0; mt < 4; ++mt)
      #pragma unroll
      for (int nt = 0; nt < 4; ++nt) {
        acc[mt][nt] = __builtin_amdgcn_mfma_f32_16x16x32_bf16(afh[mt], bfh[nt], acc[mt][nt], 0, 0, 0);
        acc[mt][nt] = __builtin_amdgcn_mfma_f32_16x16x32_bf16(afh[mt], bfl[nt], acc[mt][nt], 0, 0, 0);
        acc[mt][nt] = __builtin_amdgcn_mfma_f32_16x16x32_bf16(afl[mt], bfh[nt], acc[mt][nt], 0, 0, 0);
      }
    __syncthreads();
  }

  const float SCL = 0.18033688011112042f;  // (1/sqrt(64)) * log2(e), folded into Q
  #pragma unroll
  for (int mt = 0; mt < 4; ++mt) {
    int m_g = bm * 128 + wm * 64 + mt * 16 + quad * 4;
    #pragma unroll
    for (int nt = 0; nt < 4; ++nt) {
      int n_g = bn * 128 + wn * 64 + nt * 16 + l16;
      int p = n_g >> 10, h = (n_g >> 6) & 15, k = n_g & 63;
      #pragma unroll
      for (int r = 0; r < 4; ++r) {
        int row = m_g + r;
        int b = row >> 11, s = row & 2047;
        int bh = b * HEADS + h;
        float v = acc[mt][nt][r];
        size_t idx = ((size_t)(bh * SEQ + s)) * DKV + k;
        unsigned short hi, lo;
        if (p == 0) {
          split_bf16(v * SCL, hi, lo);
          Qh[idx] = hi; Ql[idx] = lo;
        } else {
          split_bf16(v, hi, lo);
          Kh[idx] = hi; Kl[idx] = lo;
        }
      }
    }
  }
}

// ---------- gemm_v: plain bf16 x@Wv^T -> Vt transposed. grid dim3(8=bn, 32=bm) ----------
__global__ __launch_bounds__(256, 2)
void gemm_v(const unsigned short* __restrict__ A, const unsigned short* __restrict__ Bt,
            unsigned short* __restrict__ Vt) {
  __shared__ unsigned short As[128 * 32];
  __shared__ unsigned short Bs[128 * 32];
  const int tid = threadIdx.x;
  const int w = tid >> 6, lane = tid & 63;
  const int quad = lane >> 4, l16 = lane & 15;
  const int wm = w >> 1, wn = w & 1;
  const int bn = blockIdx.x, bm = blockIdx.y;

  f32x4 acc[4][4];
  #pragma unroll
  for (int i = 0; i < 4; ++i)
    #pragma unroll
    for (int j = 0; j < 4; ++j) acc[i][j] = (f32x4){0.f, 0.f, 0.f, 0.f};

  const int r4 = lane >> 2, c4 = lane & 3;
  const unsigned short* gA0 = A  + (size_t)(bm * 128 + w * 32 + r4) * DM + c4 * 8;
  const unsigned short* gB0 = Bt + (size_t)(bn * 128 + w * 32 + r4) * DM + c4 * 8;
  unsigned short* lA0 = As + (w * 32) * 32;
  unsigned short* lA1 = As + (w * 32 + 16) * 32;
  unsigned short* lB0 = Bs + (w * 32) * 32;
  unsigned short* lB1 = Bs + (w * 32 + 16) * 32;

  for (int kk = 0; kk < DM / 32; ++kk) {
    stage16(gA0 + kk * 32,           lA0, lane);
    stage16(gA0 + kk * 32 + 16 * DM, lA1, lane);
    stage16(gB0 + kk * 32,           lB0, lane);
    stage16(gB0 + kk * 32 + 16 * DM, lB1, lane);
    asm volatile("s_waitcnt vmcnt(0)" ::: "memory");
    __syncthreads();
    bf16x8 af[4], bfr[4];
    #pragma unroll
    for (int mt = 0; mt < 4; ++mt)
      af[mt] = *(const bf16x8*)(As + (wm * 64 + mt * 16 + l16) * 32 + quad * 8);
    #pragma unroll
    for (int nt = 0; nt < 4; ++nt)
      bfr[nt] = *(const bf16x8*)(Bs + (wn * 64 + nt * 16 + l16) * 32 + quad * 8);
    #pragma unroll
    for (int mt = 0; mt < 4; ++mt)
      #pragma unroll
      for (int nt = 0; nt < 4; ++nt)
        acc[mt][nt] = __builtin_amdgcn_mfma_f32_16x16x32_bf16(af[mt], bfr[nt], acc[mt][nt], 0, 0, 0);
    __syncthreads();
  }

  #pragma unroll
  for (int mt = 0; mt < 4; ++mt) {
    int m_g = bm * 128 + wm * 64 + mt * 16 + quad * 4;
    #pragma unroll
    for (int nt = 0; nt < 4; ++nt) {
      int n_g = bn * 128 + wn * 64 + nt * 16 + l16;   // 0..1023 within V block
      int h = n_g >> 6, k = n_g & 63;
      #pragma unroll
      for (int r = 0; r < 4; ++r) {
        int row = m_g + r;
        int b = row >> 11, s = row & 2047;
        int bh = b * HEADS + h;
        Vt[((size_t)(bh * DKV + k)) * SEQ + s] = bf16_rtn(acc[mt][nt][r]);
      }
    }
  }
}

// ---------- flash: S^T = K.Q^T (split), P^T C-layout == K=16 B-layout ----------
// q-block = 64 rows (16 q-rows per wave): grid dim3(32=bh, 32=qb) = 1024 blocks
// -> 4 blocks/CU (16 waves/CU) so barrier stalls in one block are covered by
//    three other independent blocks.  id%8 = bh%8 -> each head's K/V pinned to
//    one XCD L2.
__global__ __launch_bounds__(256, 4)
void flash(const unsigned short* __restrict__ Qh, const unsigned short* __restrict__ Ql,
           const unsigned short* __restrict__ Kh, const unsigned short* __restrict__ Kl,
           const unsigned short* __restrict__ Vt, unsigned short* __restrict__ ctx) {
  __shared__ unsigned short KtH[64 * 64], KtL[64 * 64], Vts[64 * 64];  // XOR-swizzled
  const int tid = threadIdx.x;
  const int w = tid >> 6, lane = tid & 63, quad = lane >> 4, l16 = lane & 15;
  const int bh = blockIdx.x;
  const int q0 = blockIdx.y * 64;

  // Q B-frags (scaled by SCL already) for this wave's 16 q-rows, split hi/lo
  const int qrow = q0 + w * 16 + l16;
  const size_t qbase = ((size_t)(bh * SEQ + qrow)) * DKV + quad * 8;
  const bf16x8 qfh0 = *(const bf16x8*)(Qh + qbase);
  const bf16x8 qfh1 = *(const bf16x8*)(Qh + qbase + 32);
  const bf16x8 qfl0 = *(const bf16x8*)(Ql + qbase);
  const bf16x8 qfl1 = *(const bf16x8*)(Ql + qbase + 32);

  float m_run = -1e30f;
  float l_run = 0.f;
  f32x4 acc[4];
  #pragma unroll
  for (int vt = 0; vt < 4; ++vt) acc[vt] = (f32x4){0.f, 0.f, 0.f, 0.f};

  const int srow = tid >> 3, sc8 = tid & 7;   // 32 rows/pass, 8 chunks/row

  // register-prefetch pipeline
  bf16x8 rkh[2], rkl[2], rv[2];
  #pragma unroll
  for (int p = 0; p < 2; ++p) {
    int row = p * 32 + srow;
    size_t kidx = ((size_t)(bh * SEQ + row)) * DKV + sc8 * 8;
    rkh[p] = *(const bf16x8*)(Kh + kidx);
    rkl[p] = *(const bf16x8*)(Kl + kidx);
    rv[p]  = *(const bf16x8*)(Vt + ((size_t)(bh * DKV + row)) * SEQ + sc8 * 8);
  }

  for (int kt = 0; kt < SEQ / 64; ++kt) {
    __syncthreads();
    #pragma unroll
    for (int p = 0; p < 2; ++p) {
      int row = p * 32 + srow;
      int o = swz(row, sc8);
      *(bf16x8*)(KtH + o) = rkh[p];
      *(bf16x8*)(KtL + o) = rkl[p];
      *(bf16x8*)(Vts + o) = rv[p];
    }
    __syncthreads();
    if (kt + 1 < SEQ / 64) {
      int kt0 = (kt + 1) * 64;
      #pragma unroll
      for (int p = 0; p < 2; ++p) {
        int row = p * 32 + srow;
        size_t kidx = ((size_t)(bh * SEQ + kt0 + row)) * DKV + sc8 * 8;
        rkh[p] = *(const bf16x8*)(Kh + kidx);
        rkl[p] = *(const bf16x8*)(Kl + kidx);
        rv[p]  = *(const bf16x8*)(Vt + ((size_t)(bh * DKV + row)) * SEQ + kt0 + sc8 * 8);
      }
    }

    // S^T[key][q] = Kh.Qh + Kh.Ql + Kl.Qh
    f32x4 st[4];
    #pragma unroll
    for (int mt = 0; mt < 4; ++mt) {
      int rowA = mt * 16 + l16;
      bf16x8 kah0 = *(const bf16x8*)(KtH + swz(rowA, quad));
      bf16x8 kah1 = *(const bf16x8*)(KtH + swz(rowA, quad + 4));
      bf16x8 kal0 = *(const bf16x8*)(KtL + swz(rowA, quad));
      bf16x8 kal1 = *(const bf16x8*)(KtL + swz(rowA, quad + 4));
      f32x4 c = (f32x4){0.f, 0.f, 0.f, 0.f};
      c = __builtin_amdgcn_mfma_f32_16x16x32_bf16(kah0, qfh0, c, 0, 0, 0);
      c = __builtin_amdgcn_mfma_f32_16x16x32_bf16(kah1, qfh1, c, 0, 0, 0);
      c = __builtin_amdgcn_mfma_f32_16x16x32_bf16(kah0, qfl0, c, 0, 0, 0);
      c = __builtin_amdgcn_mfma_f32_16x16x32_bf16(kah1, qfl1, c, 0, 0, 0);
      c = __builtin_amdgcn_mfma_f32_16x16x32_bf16(kal0, qfh0, c, 0, 0, 0);
      c = __builtin_amdgcn_mfma_f32_16x16x32_bf16(kal1, qfh1, c, 0, 0, 0);
      st[mt] = c;
    }

    // online softmax per q-column (lane&15); vote-skip rescale when max unchanged
    bf16x4 pb[4];
    {
      float cm = -1e30f;
      #pragma unroll
      for (int mt = 0; mt < 4; ++mt)
        #pragma unroll
        for (int r = 0; r < 4; ++r) cm = fmaxf(cm, st[mt][r]);
      cm = fmaxf(cm, __shfl_xor(cm, 16));
      cm = fmaxf(cm, __shfl_xor(cm, 32));
      bool upd = cm > m_run;
      float mn = upd ? cm : m_run;
      float ssum = 0.f;
      #pragma unroll
      for (int mt = 0; mt < 4; ++mt) {
        float p0 = fast_exp2(st[mt][0] - mn);
        float p1 = fast_exp2(st[mt][1] - mn);
        float p2 = fast_exp2(st[mt][2] - mn);
        float p3 = fast_exp2(st[mt][3] - mn);
        ssum += (p0 + p1) + (p2 + p3);
        union { bf16x4 v; unsigned u2[2]; } pk;
        pk.u2[0] = pack2_bf16(p0, p1);
        pk.u2[1] = pack2_bf16(p2, p3);
        pb[mt] = pk.v;
      }
      ssum += __shfl_xor(ssum, 16);
      ssum += __shfl_xor(ssum, 32);
      if (__ballot(upd)) {
        float alpha = fast_exp2(m_run - mn);
        m_run = mn;
        l_run = l_run * alpha + ssum;
        #pragma unroll
        for (int vt = 0; vt < 4; ++vt) acc[vt] = acc[vt] * alpha;
      } else {
        l_run += ssum;
      }
    }

    // O^T[v][q] += Vt-tile[m=v][k=key] . P^T[k=key][n=q]  (K=16, B direct from regs)
    #pragma unroll
    for (int vt = 0; vt < 4; ++vt) {
      #pragma unroll
      for (int mt = 0; mt < 4; ++mt) {
        int row = vt * 16 + l16;
        int addr = row * 64 + ((((mt * 2 + (quad >> 1)) ^ (row & 7)) & 7) << 3) + (quad & 1) * 4;
        bf16x4 va = *(const bf16x4*)(Vts + addr);
        acc[vt] = mfma16x16x16_bf16(va, pb[mt], acc[vt]);
      }
    }
  }

  // epilogue: ctx[bs][h*64 + v] bf16 (perm-packed 8B stores)
  int h = bh & 15, b = bh >> 4;
  float inv = 1.0f / l_run;
  int bs = b * SEQ + q0 + w * 16 + l16;
  #pragma unroll
  for (int vt = 0; vt < 4; ++vt) {
    union { bf16x4 v; unsigned u2[2]; } pk;
    pk.u2[0] = pack2_bf16(acc[vt][0] * inv, acc[vt][1] * inv);
    pk.u2[1] = pack2_bf16(acc[vt][2] * inv, acc[vt][3] * inv);
    *(bf16x4*)(ctx + (size_t)bs * DM + h * 64 + vt * 16 + quad * 4) = pk.v;
  }
}

// ---------- GEMM2: ctx @ WoT^T -> fp32 out. grid dim3(8=bn, 32=bm) ----------
__global__ __launch_bounds__(256, 2)
void gemm_out(const unsigned short* __restrict__ A, const unsigned short* __restrict__ Bt,
              float* __restrict__ out) {
  __shared__ unsigned short As[128 * 32];
  __shared__ unsigned short Bs[128 * 32];
  const int tid = threadIdx.x;
  const int w = tid >> 6, lane = tid & 63;
  const int quad = lane >> 4, l16 = lane & 15;
  const int wm = w >> 1, wn = w & 1;
  const int bn = blockIdx.x, bm = blockIdx.y;

  f32x4 acc[4][4];
  #pragma unroll
  for (int i = 0; i < 4; ++i)
    #pragma unroll
    for (int j = 0; j < 4; ++j) acc[i][j] = (f32x4){0.f, 0.f, 0.f, 0.f};

  const int r4 = lane >> 2, c4 = lane & 3;
  const unsigned short* gA0 = A  + (size_t)(bm * 128 + w * 32 + r4) * DM + c4 * 8;
  const unsigned short* gB0 = Bt + (size_t)(bn * 128 + w * 32 + r4) * DM + c4 * 8;
  unsigned short* lA0 = As + (w * 32) * 32;
  unsigned short* lA1 = As + (w * 32 + 16) * 32;
  unsigned short* lB0 = Bs + (w * 32) * 32;
  unsigned short* lB1 = Bs + (w * 32 + 16) * 32;

  for (int kk = 0; kk < DM / 32; ++kk) {
    stage16(gA0 + kk * 32,           lA0, lane);
    stage16(gA0 + kk * 32 + 16 * DM, lA1, lane);
    stage16(gB0 + kk * 32,           lB0, lane);
    stage16(gB0 + kk * 32 + 16 * DM, lB1, lane);
    asm volatile("s_waitcnt vmcnt(0)" ::: "memory");
    __syncthreads();
    bf16x8 af[4], bfr[4];
    #pragma unroll
    for (int mt = 0; mt < 4; ++mt)
      af[mt] = *(const bf16x8*)(As + (wm * 64 + mt * 16 + l16) * 32 + quad * 8);
    #pragma unroll
    for (int nt = 0; nt < 4; ++nt)
      bfr[nt] = *(const bf16x8*)(Bs + (wn * 64 + nt * 16 + l16) * 32 + quad * 8);
    #pragma unroll
    for (int mt = 0; mt < 4; ++mt)
      #pragma unroll
      for (int nt = 0; nt < 4; ++nt)
        acc[mt][nt] = __builtin_amdgcn_mfma_f32_16x16x32_bf16(af[mt], bfr[nt], acc[mt][nt], 0, 0, 0);
    __syncthreads();
  }

  #pragma unroll
  for (int mt = 0; mt < 4; ++mt) {
    int m_g = bm * 128 + wm * 64 + mt * 16 + quad * 4;
    #pragma unroll
    for (int nt = 0; nt < 4; ++nt) {
      int n_g = bn * 128 + wn * 64 + nt * 16 + l16;
      #pragma unroll
      for (int r = 0; r < 4; ++r)
        out[(size_t)(m_g + r) * DM + n_g] = acc[mt][nt][r];
    }
  }
}

// ---------- launch ----------
extern "C" void kernel_launch(void* const* d_in, const int* in_sizes, int n_in,
                              void* d_out, int out_size, void* d_ws, size_t ws_size,
                              hipStream_t stream) {
  const float* x  = (const float*)d_in[0];
  const float* Wk = (const float*)d_in[1];
  const float* Wq = (const float*)d_in[2];
  const float* Wv = (const float*)d_in[3];
  const float* Wo = (const float*)d_in[4];
  float* out = (float*)d_out;

  unsigned short* xh  = (unsigned short*)d_ws;                  // [4096][1024]
  unsigned short* xl  = xh  + (size_t)BS * DM;
  unsigned short* Wh  = xl  + (size_t)BS * DM;                  // [3072][1024]
  unsigned short* Wl  = Wh  + (size_t)3 * DM * DM;
  unsigned short* WoT = Wl  + (size_t)3 * DM * DM;              // [1024][1024]
  unsigned short* Qh  = WoT + (size_t)DM * DM;                  // [32][2048][64]
  unsigned short* Ql  = Qh  + (size_t)BHD * SEQ * DKV;
  unsigned short* Kh  = Ql  + (size_t)BHD * SEQ * DKV;
  unsigned short* Kl  = Kh  + (size_t)BHD * SEQ * DKV;
  unsigned short* Vtb = Kl  + (size_t)BHD * SEQ * DKV;          // [32][64][2048]
  unsigned short* ctx = Vtb + (size_t)BHD * SEQ * DKV;          // [4096][1024]

  cvt_x_split<<<(BS * DM) / (256 * 8), 256, 0, stream>>>(x, xh, xl);
  pack_qkv_split<<<3 * 16 * 16, 256, 0, stream>>>(Wq, Wk, Wv, Wh, Wl);
  pack_wo<<<16 * 16, 256, 0, stream>>>(Wo, WoT);
  gemm_qk<<<dim3(16, 32), 256, 0, stream>>>(xh, xl, Wh, Wl, Qh, Ql, Kh, Kl);
  gemm_v<<<dim3(8, 32), 256, 0, stream>>>(xh, Wh + (size_t)2048 * DM, Vtb);
  flash<<<dim3(BHD, SEQ / 64), 256, 0, stream>>>(Qh, Ql, Kh, Kl, Vtb, ctx);
  gemm_out<<<dim3(8, 32), 256, 0, stream>>>(ctx, WoT, out);
}

// Round 2
// 272.129 us; speedup vs baseline: 1.0468x; 1.0468x over previous
//
#include <hip/hip_runtime.h>
#include <hip/hip_bf16.h>
#include <stdint.h>

#define DM   1024
#define DKV  64
#define HEADS 16
#define BATCH 2
#define SEQ  2048
#define BS   (BATCH*SEQ)    // 4096
#define BHD  (BATCH*HEADS)  // 32

typedef __attribute__((ext_vector_type(8))) short bf16x8;
typedef __attribute__((ext_vector_type(4))) short bf16x4;
typedef __attribute__((ext_vector_type(4))) float f32x4;

// ---------- helpers ----------
__device__ inline unsigned fb(float f) { union { float f; unsigned u; } v; v.f = f; return v.u; }

__device__ inline unsigned short bf16_rtn(float f) {
  unsigned u = fb(f);
  unsigned r = u + 0x7fffu + ((u >> 16) & 1u);
  return (unsigned short)(r >> 16);
}
__device__ inline float bf16_to_f(unsigned short h) {
  union { unsigned u; float f; } v; v.u = ((unsigned)h) << 16; return v.f;
}
// split x ≈ hi + lo, |lo| <= 2^-9 |x|, residual ~2^-18
__device__ inline void split_bf16(float x, unsigned short& hi, unsigned short& lo) {
  hi = bf16_rtn(x);
  lo = bf16_rtn(x - bf16_to_f(hi));
}
// pack two fp32 -> two bf16 (round-half-up) in one dword via v_perm_b32
__device__ inline unsigned pack2_bf16(float lo_elem, float hi_elem) {
  return __builtin_amdgcn_perm(fb(hi_elem) + 0x8000u, fb(lo_elem) + 0x8000u, 0x07060302u);
}

__device__ inline float fast_exp2(float x) {
#if __has_builtin(__builtin_amdgcn_exp2f)
  return __builtin_amdgcn_exp2f(x);
#else
  return exp2f(x);
#endif
}

__device__ inline f32x4 mfma16x16x16_bf16(bf16x4 a, bf16x4 b, f32x4 c) {
#if __has_builtin(__builtin_amdgcn_mfma_f32_16x16x16bf16_1k)
  return __builtin_amdgcn_mfma_f32_16x16x16bf16_1k(a, b, c, 0, 0, 0);
#else
  asm volatile("v_mfma_f32_16x16x16_bf16 %0, %1, %2, %0" : "+v"(c) : "v"(a), "v"(b));
  return c;
#endif
}

// stage 16B/lane: async direct-to-LDS (dest = wave-uniform base + lane*16)
__device__ inline void stage16(const unsigned short* g, unsigned short* lds_base, int lane) {
#if __has_builtin(__builtin_amdgcn_global_load_lds)
  __builtin_amdgcn_global_load_lds((__attribute__((address_space(1))) void*)(g),
                                   (__attribute__((address_space(3))) void*)(lds_base),
                                   16, 0, 0);
#else
  *(bf16x8*)(lds_base + lane * 8) = *(const bf16x8*)g;
#endif
}

// XOR-swizzled LDS index for a 64-col bf16 tile (8 chunks of 8 shorts per row)
__device__ inline int swz(int row, int chunk) {
  return row * 64 + (((chunk ^ (row & 7)) & 7) << 3);
}

// ---------- pack kernels ----------
__global__ void cvt_x_split(const float* __restrict__ x,
                            unsigned short* __restrict__ xh, unsigned short* __restrict__ xl) {
  int i = (blockIdx.x * 256 + threadIdx.x) * 8;
  bf16x8 oh, ol;
  #pragma unroll
  for (int j = 0; j < 8; ++j) {
    unsigned short hi, lo;
    split_bf16(x[i + j], hi, lo);
    oh[j] = (short)hi; ol[j] = (short)lo;
  }
  *(bf16x8*)(xh + i) = oh;
  *(bf16x8*)(xl + i) = ol;
}

// WcatT[c'][m] split, c' = p*1024 + h*64 + k  (p: 0=Q,1=K,2=V), from W_p[h][m][k]
__global__ void pack_qkv_split(const float* __restrict__ Wq, const float* __restrict__ Wk,
                               const float* __restrict__ Wv,
                               unsigned short* __restrict__ Wh, unsigned short* __restrict__ Wl) {
  __shared__ float tile[64][65];
  int bid = blockIdx.x;               // p*256 + h*16 + mt
  int p = bid >> 8, h = (bid >> 4) & 15, mt = bid & 15;
  const float* W = (p == 0) ? Wq : (p == 1) ? Wk : Wv;
  const float* src = W + (size_t)h * (DM * DKV);
  int t = threadIdx.x;
  int m0 = mt * 64;
  #pragma unroll
  for (int pass = 0; pass < 16; ++pass) {
    int row = pass * 4 + (t >> 6), col = t & 63;
    tile[row][col] = src[(size_t)(m0 + row) * DKV + col];
  }
  __syncthreads();
  int cbase = p * 1024 + h * 64;
  #pragma unroll
  for (int pass = 0; pass < 16; ++pass) {
    int krow = pass * 4 + (t >> 6), mcol = t & 63;
    unsigned short hi, lo;
    split_bf16(tile[mcol][krow], hi, lo);
    size_t idx = (size_t)(cbase + krow) * DM + m0 + mcol;
    Wh[idx] = hi; Wl[idx] = lo;
  }
}

// WoT[mo][c] = Wo[c][mo], single bf16
__global__ void pack_wo(const float* __restrict__ Wo, unsigned short* __restrict__ WoT) {
  __shared__ float tile[64][65];
  int ib = blockIdx.x >> 4, jb = blockIdx.x & 15;
  int t = threadIdx.x;
  #pragma unroll
  for (int pass = 0; pass < 16; ++pass) {
    int row = pass * 4 + (t >> 6), col = t & 63;
    tile[row][col] = Wo[(size_t)(ib * 64 + row) * DM + jb * 64 + col];
  }
  __syncthreads();
  #pragma unroll
  for (int pass = 0; pass < 16; ++pass) {
    int a = pass * 4 + (t >> 6), b = t & 63;
    WoT[(size_t)(jb * 64 + a) * DM + ib * 64 + b] = bf16_rtn(tile[b][a]);
  }
}

// ---------- gemm_qk: split-precision x@Wqk^T, N=2048, tile 128x128x32 ----------
// grid dim3(16=bn, 32=bm): id%8 = bn%8 -> weight tiles pinned per XCD
__global__ __launch_bounds__(256, 2)
void gemm_qk(const unsigned short* __restrict__ Ah, const unsigned short* __restrict__ Al,
             const unsigned short* __restrict__ Bh, const unsigned short* __restrict__ Bl,
             unsigned short* __restrict__ Qh, unsigned short* __restrict__ Ql,
             unsigned short* __restrict__ Kh, unsigned short* __restrict__ Kl) {
  __shared__ unsigned short AsH[128 * 32], AsL[128 * 32];
  __shared__ unsigned short BsH[128 * 32], BsL[128 * 32];
  const int tid = threadIdx.x;
  const int w = tid >> 6, lane = tid & 63;
  const int quad = lane >> 4, l16 = lane & 15;
  const int wm = w >> 1, wn = w & 1;
  const int bn = blockIdx.x, bm = blockIdx.y;

  f32x4 acc[4][4];
  #pragma unroll
  for (int i = 0; i < 4; ++i)
    #pragma unroll
    for (int j = 0; j < 4; ++j) acc[i][j] = (f32x4){0.f, 0.f, 0.f, 0.f};

  const int r4 = lane >> 2, c4 = lane & 3;
  const size_t offA = (size_t)(bm * 128 + w * 32 + r4) * DM + c4 * 8;
  const size_t offB = (size_t)(bn * 128 + w * 32 + r4) * DM + c4 * 8;
  unsigned short* lAh0 = AsH + (w * 32) * 32;      unsigned short* lAh1 = AsH + (w * 32 + 16) * 32;
  unsigned short* lAl0 = AsL + (w * 32) * 32;      unsigned short* lAl1 = AsL + (w * 32 + 16) * 32;
  unsigned short* lBh0 = BsH + (w * 32) * 32;      unsigned short* lBh1 = BsH + (w * 32 + 16) * 32;
  unsigned short* lBl0 = BsL + (w * 32) * 32;      unsigned short* lBl1 = BsL + (w * 32 + 16) * 32;

  for (int kk = 0; kk < DM / 32; ++kk) {
    stage16(Ah + offA + kk * 32,           lAh0, lane);
    stage16(Ah + offA + kk * 32 + 16 * DM, lAh1, lane);
    stage16(Al + offA + kk * 32,           lAl0, lane);
    stage16(Al + offA + kk * 32 + 16 * DM, lAl1, lane);
    stage16(Bh + offB + kk * 32,           lBh0, lane);
    stage16(Bh + offB + kk * 32 + 16 * DM, lBh1, lane);
    stage16(Bl + offB + kk * 32,           lBl0, lane);
    stage16(Bl + offB + kk * 32 + 16 * DM, lBl1, lane);
    asm volatile("s_waitcnt vmcnt(0)" ::: "memory");
    __syncthreads();
    bf16x8 afh[4], afl[4], bfh[4], bfl[4];
    #pragma unroll
    for (int mt = 0; mt < 4; ++mt) {
      afh[mt] = *(const bf16x8*)(AsH + (wm * 64 + mt * 16 + l16) * 32 + quad * 8);
      afl[mt] = *(const bf16x8*)(AsL + (wm * 64 + mt * 16 + l16) * 32 + quad * 8);
    }
    #pragma unroll
    for (int nt = 0; nt < 4; ++nt) {
      bfh[nt] = *(const bf16x8*)(BsH + (wn * 64 + nt * 16 + l16) * 32 + quad * 8);
      bfl[nt] = *(const bf16x8*)(BsL + (wn * 64 + nt * 16 + l16) * 32 + quad * 8);
    }
    #pragma unroll
    for (int mt = 0; mt < 4; ++mt)
      #pragma unroll
      for (int nt = 0; nt < 4; ++nt) {
        acc[mt][nt] = __builtin_amdgcn_mfma_f32_16x16x32_bf16(afh[mt], bfh[nt], acc[mt][nt], 0, 0, 0);
        acc[mt][nt] = __builtin_amdgcn_mfma_f32_16x16x32_bf16(afh[mt], bfl[nt], acc[mt][nt], 0, 0, 0);
        acc[mt][nt] = __builtin_amdgcn_mfma_f32_16x16x32_bf16(afl[mt], bfh[nt], acc[mt][nt], 0, 0, 0);
      }
    __syncthreads();
  }

  const float SCL = 0.18033688011112042f;  // (1/sqrt(64)) * log2(e), folded into Q
  #pragma unroll
  for (int mt = 0; mt < 4; ++mt) {
    int m_g = bm * 128 + wm * 64 + mt * 16 + quad * 4;
    #pragma unroll
    for (int nt = 0; nt < 4; ++nt) {
      int n_g = bn * 128 + wn * 64 + nt * 16 + l16;
      int p = n_g >> 10, h = (n_g >> 6) & 15, k = n_g & 63;
      #pragma unroll
      for (int r = 0; r < 4; ++r) {
        int row = m_g + r;
        int b = row >> 11, s = row & 2047;
        int bh = b * HEADS + h;
        float v = acc[mt][nt][r];
        size_t idx = ((size_t)(bh * SEQ + s)) * DKV + k;
        unsigned short hi, lo;
        if (p == 0) {
          split_bf16(v * SCL, hi, lo);
          Qh[idx] = hi; Ql[idx] = lo;
        } else {
          split_bf16(v, hi, lo);
          Kh[idx] = hi; Kl[idx] = lo;
        }
      }
    }
  }
}

// ---------- gemm_v: plain bf16 x@Wv^T -> Vt transposed. grid dim3(8=bn, 32=bm) ----------
__global__ __launch_bounds__(256, 2)
void gemm_v(const unsigned short* __restrict__ A, const unsigned short* __restrict__ Bt,
            unsigned short* __restrict__ Vt) {
  __shared__ unsigned short As[128 * 32];
  __shared__ unsigned short Bs[128 * 32];
  const int tid = threadIdx.x;
  const int w = tid >> 6, lane = tid & 63;
  const int quad = lane >> 4, l16 = lane & 15;
  const int wm = w >> 1, wn = w & 1;
  const int bn = blockIdx.x, bm = blockIdx.y;

  f32x4 acc[4][4];
  #pragma unroll
  for (int i = 0; i < 4; ++i)
    #pragma unroll
    for (int j = 0; j < 4; ++j) acc[i][j] = (f32x4){0.f, 0.f, 0.f, 0.f};

  const int r4 = lane >> 2, c4 = lane & 3;
  const unsigned short* gA0 = A  + (size_t)(bm * 128 + w * 32 + r4) * DM + c4 * 8;
  const unsigned short* gB0 = Bt + (size_t)(bn * 128 + w * 32 + r4) * DM + c4 * 8;
  unsigned short* lA0 = As + (w * 32) * 32;
  unsigned short* lA1 = As + (w * 32 + 16) * 32;
  unsigned short* lB0 = Bs + (w * 32) * 32;
  unsigned short* lB1 = Bs + (w * 32 + 16) * 32;

  for (int kk = 0; kk < DM / 32; ++kk) {
    stage16(gA0 + kk * 32,           lA0, lane);
    stage16(gA0 + kk * 32 + 16 * DM, lA1, lane);
    stage16(gB0 + kk * 32,           lB0, lane);
    stage16(gB0 + kk * 32 + 16 * DM, lB1, lane);
    asm volatile("s_waitcnt vmcnt(0)" ::: "memory");
    __syncthreads();
    bf16x8 af[4], bfr[4];
    #pragma unroll
    for (int mt = 0; mt < 4; ++mt)
      af[mt] = *(const bf16x8*)(As + (wm * 64 + mt * 16 + l16) * 32 + quad * 8);
    #pragma unroll
    for (int nt = 0; nt < 4; ++nt)
      bfr[nt] = *(const bf16x8*)(Bs + (wn * 64 + nt * 16 + l16) * 32 + quad * 8);
    #pragma unroll
    for (int mt = 0; mt < 4; ++mt)
      #pragma unroll
      for (int nt = 0; nt < 4; ++nt)
        acc[mt][nt] = __builtin_amdgcn_mfma_f32_16x16x32_bf16(af[mt], bfr[nt], acc[mt][nt], 0, 0, 0);
    __syncthreads();
  }

  #pragma unroll
  for (int mt = 0; mt < 4; ++mt) {
    int m_g = bm * 128 + wm * 64 + mt * 16 + quad * 4;
    #pragma unroll
    for (int nt = 0; nt < 4; ++nt) {
      int n_g = bn * 128 + wn * 64 + nt * 16 + l16;   // 0..1023 within V block
      int h = n_g >> 6, k = n_g & 63;
      #pragma unroll
      for (int r = 0; r < 4; ++r) {
        int row = m_g + r;
        int b = row >> 11, s = row & 2047;
        int bh = b * HEADS + h;
        Vt[((size_t)(bh * DKV + k)) * SEQ + s] = bf16_rtn(acc[mt][nt][r]);
      }
    }
  }
}

// ---------- flash: S^T = K.Q^T (split), P^T C-layout == K=16 B-layout ----------
// q-block = 128 rows (32 q-rows per wave, qt=2) — best K-fragment amortization.
// Staging: global_load_lds DMA into DOUBLE-BUFFERED swizzled LDS; the XOR swizzle
// is applied by pre-swizzling the per-lane GLOBAL source address (the permutation
// csrc = (lane&7)^(lane>>3) is an involution), LDS dest stays linear (HW adds
// lane*16). ONE barrier per kt-iteration instead of two; no ds_writes, no
// register prefetch.  grid dim3(32=bh, 16=qb); id%8 -> head's K/V pinned per XCD.
__global__ __launch_bounds__(256, 2)
void flash(const unsigned short* __restrict__ Qh, const unsigned short* __restrict__ Ql,
           const unsigned short* __restrict__ Kh, const unsigned short* __restrict__ Kl,
           const unsigned short* __restrict__ Vt, unsigned short* __restrict__ ctx) {
  __shared__ unsigned short KtH[2][64 * 64], KtL[2][64 * 64], Vts[2][64 * 64];
  const int tid = threadIdx.x;
  const int w = tid >> 6, lane = tid & 63, quad = lane >> 4, l16 = lane & 15;
  const int bh = blockIdx.x;
  const int q0 = blockIdx.y * 128;

  // Q B-frags (scaled by SCL already): [n=q][k=d], split hi/lo
  bf16x8 qfh[2][2], qfl[2][2];
  #pragma unroll
  for (int qt = 0; qt < 2; ++qt) {
    int qrow = q0 + w * 32 + qt * 16 + l16;
    size_t base = ((size_t)(bh * SEQ + qrow)) * DKV + quad * 8;
    qfh[qt][0] = *(const bf16x8*)(Qh + base);
    qfh[qt][1] = *(const bf16x8*)(Qh + base + 32);
    qfl[qt][0] = *(const bf16x8*)(Ql + base);
    qfl[qt][1] = *(const bf16x8*)(Ql + base + 32);
  }

  float m_run[2] = {-1e30f, -1e30f};
  float l_run[2] = {0.f, 0.f};
  f32x4 acc[2][4];
  #pragma unroll
  for (int qt = 0; qt < 2; ++qt)
    #pragma unroll
    for (int vt = 0; vt < 4; ++vt) acc[qt][vt] = (f32x4){0.f, 0.f, 0.f, 0.f};

  // staging geometry: wave w stages rows [w*16, w*16+16) of each tile, 2 passes
  // of 8 rows (1 KB per global_load_lds).  lane -> row = base + (lane>>3),
  // source chunk csrc = (lane&7) ^ (lane>>3)  (== (lane&7) ^ (row&7)).
  const int srow = w * 16 + (lane >> 3);
  const int csrc = (lane & 7) ^ (lane >> 3);
  const unsigned short* kh_src = Kh + ((size_t)(bh * SEQ) + srow) * DKV + csrc * 8;
  const unsigned short* kl_src = Kl + ((size_t)(bh * SEQ) + srow) * DKV + csrc * 8;
  const unsigned short* v_src  = Vt + ((size_t)(bh * DKV) + srow) * SEQ + csrc * 8;

  #define STAGE(buf, kt0)                                                     \
    do {                                                                      \
      unsigned short* dH = &KtH[buf][(w * 16) * 64];                          \
      unsigned short* dL = &KtL[buf][(w * 16) * 64];                          \
      unsigned short* dV = &Vts[buf][(w * 16) * 64];                          \
      stage16(kh_src + (size_t)(kt0) * DKV,            dH,       lane);       \
      stage16(kh_src + (size_t)(kt0) * DKV + 8 * DKV,  dH + 512, lane);       \
      stage16(kl_src + (size_t)(kt0) * DKV,            dL,       lane);       \
      stage16(kl_src + (size_t)(kt0) * DKV + 8 * DKV,  dL + 512, lane);       \
      stage16(v_src  + (kt0),                          dV,       lane);       \
      stage16(v_src  + (kt0) + 8 * SEQ,                dV + 512, lane);       \
    } while (0)

  STAGE(0, 0);
  asm volatile("s_waitcnt vmcnt(0)" ::: "memory");
  __syncthreads();
  int cur = 0;

  for (int kt = 0; kt < SEQ / 64; ++kt) {
    // issue next tile's DMA early; it flies under this iteration's compute
    if (kt + 1 < SEQ / 64) STAGE(cur ^ 1, (kt + 1) * 64);

    const unsigned short* kH = KtH[cur];
    const unsigned short* kL = KtL[cur];
    const unsigned short* vS = Vts[cur];

    // S^T[key][q] = Kh.Qh + Kh.Ql + Kl.Qh
    f32x4 st[4][2];
    #pragma unroll
    for (int mt = 0; mt < 4; ++mt) {
      int rowA = mt * 16 + l16;
      bf16x8 kah0 = *(const bf16x8*)(kH + swz(rowA, quad));
      bf16x8 kah1 = *(const bf16x8*)(kH + swz(rowA, quad + 4));
      bf16x8 kal0 = *(const bf16x8*)(kL + swz(rowA, quad));
      bf16x8 kal1 = *(const bf16x8*)(kL + swz(rowA, quad + 4));
      #pragma unroll
      for (int qt = 0; qt < 2; ++qt) {
        f32x4 c = (f32x4){0.f, 0.f, 0.f, 0.f};
        c = __builtin_amdgcn_mfma_f32_16x16x32_bf16(kah0, qfh[qt][0], c, 0, 0, 0);
        c = __builtin_amdgcn_mfma_f32_16x16x32_bf16(kah1, qfh[qt][1], c, 0, 0, 0);
        c = __builtin_amdgcn_mfma_f32_16x16x32_bf16(kah0, qfl[qt][0], c, 0, 0, 0);
        c = __builtin_amdgcn_mfma_f32_16x16x32_bf16(kah1, qfl[qt][1], c, 0, 0, 0);
        c = __builtin_amdgcn_mfma_f32_16x16x32_bf16(kal0, qfh[qt][0], c, 0, 0, 0);
        c = __builtin_amdgcn_mfma_f32_16x16x32_bf16(kal1, qfh[qt][1], c, 0, 0, 0);
        st[mt][qt] = c;
      }
    }

    // online softmax per q-column (lane&15); vote-skip rescale when max unchanged
    bf16x4 pb[2][4];
    #pragma unroll
    for (int qt = 0; qt < 2; ++qt) {
      float cm = -1e30f;
      #pragma unroll
      for (int mt = 0; mt < 4; ++mt)
        #pragma unroll
        for (int r = 0; r < 4; ++r) cm = fmaxf(cm, st[mt][qt][r]);
      cm = fmaxf(cm, __shfl_xor(cm, 16));
      cm = fmaxf(cm, __shfl_xor(cm, 32));
      bool upd = cm > m_run[qt];
      float mn = upd ? cm : m_run[qt];
      float ssum = 0.f;
      #pragma unroll
      for (int mt = 0; mt < 4; ++mt) {
        float p0 = fast_exp2(st[mt][qt][0] - mn);
        float p1 = fast_exp2(st[mt][qt][1] - mn);
        float p2 = fast_exp2(st[mt][qt][2] - mn);
        float p3 = fast_exp2(st[mt][qt][3] - mn);
        ssum += (p0 + p1) + (p2 + p3);
        union { bf16x4 v; unsigned u2[2]; } pk;
        pk.u2[0] = pack2_bf16(p0, p1);
        pk.u2[1] = pack2_bf16(p2, p3);
        pb[qt][mt] = pk.v;
      }
      ssum += __shfl_xor(ssum, 16);
      ssum += __shfl_xor(ssum, 32);
      if (__ballot(upd)) {
        float alpha = fast_exp2(m_run[qt] - mn);
        m_run[qt] = mn;
        l_run[qt] = l_run[qt] * alpha + ssum;
        #pragma unroll
        for (int vt = 0; vt < 4; ++vt) acc[qt][vt] = acc[qt][vt] * alpha;
      } else {
        l_run[qt] += ssum;
      }
    }

    // O^T[v][q] += Vt-tile[m=v][k=key] . P^T[k=key][n=q]  (K=16, B direct from regs)
    #pragma unroll
    for (int vt = 0; vt < 4; ++vt) {
      #pragma unroll
      for (int mt = 0; mt < 4; ++mt) {
        int row = vt * 16 + l16;
        int addr = row * 64 + ((((mt * 2 + (quad >> 1)) ^ (row & 7)) & 7) << 3) + (quad & 1) * 4;
        bf16x4 va = *(const bf16x4*)(vS + addr);
        #pragma unroll
        for (int qt = 0; qt < 2; ++qt)
          acc[qt][vt] = mfma16x16x16_bf16(va, pb[qt][mt], acc[qt][vt]);
      }
    }

    // drain this wave's next-tile DMA, then one barrier: all waves done reading
    // buf[cur] AND all staged writes to buf[cur^1] visible
    asm volatile("s_waitcnt vmcnt(0)" ::: "memory");
    __syncthreads();
    cur ^= 1;
  }
  #undef STAGE

  // epilogue: ctx[bs][h*64 + v] bf16 (perm-packed 8B stores)
  int h = bh & 15, b = bh >> 4;
  #pragma unroll
  for (int qt = 0; qt < 2; ++qt) {
    float inv = 1.0f / l_run[qt];
    int bs = b * SEQ + q0 + w * 32 + qt * 16 + l16;
    #pragma unroll
    for (int vt = 0; vt < 4; ++vt) {
      union { bf16x4 v; unsigned u2[2]; } pk;
      pk.u2[0] = pack2_bf16(acc[qt][vt][0] * inv, acc[qt][vt][1] * inv);
      pk.u2[1] = pack2_bf16(acc[qt][vt][2] * inv, acc[qt][vt][3] * inv);
      *(bf16x4*)(ctx + (size_t)bs * DM + h * 64 + vt * 16 + quad * 4) = pk.v;
    }
  }
}

// ---------- GEMM2: ctx @ WoT^T -> fp32 out. grid dim3(8=bn, 32=bm) ----------
__global__ __launch_bounds__(256, 2)
void gemm_out(const unsigned short* __restrict__ A, const unsigned short* __restrict__ Bt,
              float* __restrict__ out) {
  __shared__ unsigned short As[128 * 32];
  __shared__ unsigned short Bs[128 * 32];
  const int tid = threadIdx.x;
  const int w = tid >> 6, lane = tid & 63;
  const int quad = lane >> 4, l16 = lane & 15;
  const int wm = w >> 1, wn = w & 1;
  const int bn = blockIdx.x, bm = blockIdx.y;

  f32x4 acc[4][4];
  #pragma unroll
  for (int i = 0; i < 4; ++i)
    #pragma unroll
    for (int j = 0; j < 4; ++j) acc[i][j] = (f32x4){0.f, 0.f, 0.f, 0.f};

  const int r4 = lane >> 2, c4 = lane & 3;
  const unsigned short* gA0 = A  + (size_t)(bm * 128 + w * 32 + r4) * DM + c4 * 8;
  const unsigned short* gB0 = Bt + (size_t)(bn * 128 + w * 32 + r4) * DM + c4 * 8;
  unsigned short* lA0 = As + (w * 32) * 32;
  unsigned short* lA1 = As + (w * 32 + 16) * 32;
  unsigned short* lB0 = Bs + (w * 32) * 32;
  unsigned short* lB1 = Bs + (w * 32 + 16) * 32;

  for (int kk = 0; kk < DM / 32; ++kk) {
    stage16(gA0 + kk * 32,           lA0, lane);
    stage16(gA0 + kk * 32 + 16 * DM, lA1, lane);
    stage16(gB0 + kk * 32,           lB0, lane);
    stage16(gB0 + kk * 32 + 16 * DM, lB1, lane);
    asm volatile("s_waitcnt vmcnt(0)" ::: "memory");
    __syncthreads();
    bf16x8 af[4], bfr[4];
    #pragma unroll
    for (int mt = 0; mt < 4; ++mt)
      af[mt] = *(const bf16x8*)(As + (wm * 64 + mt * 16 + l16) * 32 + quad * 8);
    #pragma unroll
    for (int nt = 0; nt < 4; ++nt)
      bfr[nt] = *(const bf16x8*)(Bs + (wn * 64 + nt * 16 + l16) * 32 + quad * 8);
    #pragma unroll
    for (int mt = 0; mt < 4; ++mt)
      #pragma unroll
      for (int nt = 0; nt < 4; ++nt)
        acc[mt][nt] = __builtin_amdgcn_mfma_f32_16x16x32_bf16(af[mt], bfr[nt], acc[mt][nt], 0, 0, 0);
    __syncthreads();
  }

  #pragma unroll
  for (int mt = 0; mt < 4; ++mt) {
    int m_g = bm * 128 + wm * 64 + mt * 16 + quad * 4;
    #pragma unroll
    for (int nt = 0; nt < 4; ++nt) {
      int n_g = bn * 128 + wn * 64 + nt * 16 + l16;
      #pragma unroll
      for (int r = 0; r < 4; ++r)
        out[(size_t)(m_g + r) * DM + n_g] = acc[mt][nt][r];
    }
  }
}

// ---------- launch ----------
extern "C" void kernel_launch(void* const* d_in, const int* in_sizes, int n_in,
                              void* d_out, int out_size, void* d_ws, size_t ws_size,
                              hipStream_t stream) {
  const float* x  = (const float*)d_in[0];
  const float* Wk = (const float*)d_in[1];
  const float* Wq = (const float*)d_in[2];
  const float* Wv = (const float*)d_in[3];
  const float* Wo = (const float*)d_in[4];
  float* out = (float*)d_out;

  unsigned short* xh  = (unsigned short*)d_ws;                  // [4096][1024]
  unsigned short* xl  = xh  + (size_t)BS * DM;
  unsigned short* Wh  = xl  + (size_t)BS * DM;                  // [3072][1024]
  unsigned short* Wl  = Wh  + (size_t)3 * DM * DM;
  unsigned short* WoT = Wl  + (size_t)3 * DM * DM;              // [1024][1024]
  unsigned short* Qh  = WoT + (size_t)DM * DM;                  // [32][2048][64]
  unsigned short* Ql  = Qh  + (size_t)BHD * SEQ * DKV;
  unsigned short* Kh  = Ql  + (size_t)BHD * SEQ * DKV;
  unsigned short* Kl  = Kh  + (size_t)BHD * SEQ * DKV;
  unsigned short* Vtb = Kl  + (size_t)BHD * SEQ * DKV;          // [32][64][2048]
  unsigned short* ctx = Vtb + (size_t)BHD * SEQ * DKV;          // [4096][1024]

  cvt_x_split<<<(BS * DM) / (256 * 8), 256, 0, stream>>>(x, xh, xl);
  pack_qkv_split<<<3 * 16 * 16, 256, 0, stream>>>(Wq, Wk, Wv, Wh, Wl);
  pack_wo<<<16 * 16, 256, 0, stream>>>(Wo, WoT);
  gemm_qk<<<dim3(16, 32), 256, 0, stream>>>(xh, xl, Wh, Wl, Qh, Ql, Kh, Kl);
  gemm_v<<<dim3(8, 32), 256, 0, stream>>>(xh, Wh + (size_t)2048 * DM, Vtb);
  flash<<<dim3(BHD, SEQ / 128), 256, 0, stream>>>(Qh, Ql, Kh, Kl, Vtb, ctx);
  gemm_out<<<dim3(8, 32), 256, 0, stream>>>(ctx, WoT, out);
}

// Round 3
// 242.019 us; speedup vs baseline: 1.1770x; 1.1244x over previous
//
#include <hip/hip_runtime.h>
#include <hip/hip_bf16.h>
#include <stdint.h>

#define DM   1024
#define DKV  64
#define HEADS 16
#define BATCH 2
#define SEQ  2048
#define BS   (BATCH*SEQ)    // 4096
#define BHD  (BATCH*HEADS)  // 32

typedef __attribute__((ext_vector_type(8))) short bf16x8;
typedef __attribute__((ext_vector_type(4))) short bf16x4;
typedef __attribute__((ext_vector_type(4))) float f32x4;

// ---------- helpers ----------
__device__ inline unsigned fb(float f) { union { float f; unsigned u; } v; v.f = f; return v.u; }

__device__ inline unsigned short bf16_rtn(float f) {
  unsigned u = fb(f);
  unsigned r = u + 0x7fffu + ((u >> 16) & 1u);
  return (unsigned short)(r >> 16);
}
__device__ inline float bf16_to_f(unsigned short h) {
  union { unsigned u; float f; } v; v.u = ((unsigned)h) << 16; return v.f;
}
// split x ≈ hi + lo, |lo| <= 2^-9 |x|, residual ~2^-18
__device__ inline void split_bf16(float x, unsigned short& hi, unsigned short& lo) {
  hi = bf16_rtn(x);
  lo = bf16_rtn(x - bf16_to_f(hi));
}
// pack two fp32 -> two bf16 (round-half-up) in one dword via v_perm_b32
__device__ inline unsigned pack2_bf16(float lo_elem, float hi_elem) {
  return __builtin_amdgcn_perm(fb(hi_elem) + 0x8000u, fb(lo_elem) + 0x8000u, 0x07060302u);
}

__device__ inline float fast_exp2(float x) {
#if __has_builtin(__builtin_amdgcn_exp2f)
  return __builtin_amdgcn_exp2f(x);
#else
  return exp2f(x);
#endif
}

__device__ inline f32x4 mfma16x16x16_bf16(bf16x4 a, bf16x4 b, f32x4 c) {
#if __has_builtin(__builtin_amdgcn_mfma_f32_16x16x16bf16_1k)
  return __builtin_amdgcn_mfma_f32_16x16x16bf16_1k(a, b, c, 0, 0, 0);
#else
  asm volatile("v_mfma_f32_16x16x16_bf16 %0, %1, %2, %0" : "+v"(c) : "v"(a), "v"(b));
  return c;
#endif
}

// stage 16B/lane: async direct-to-LDS (dest = wave-uniform base + lane*16)
__device__ inline void stage16(const unsigned short* g, unsigned short* lds_base, int lane) {
#if __has_builtin(__builtin_amdgcn_global_load_lds)
  __builtin_amdgcn_global_load_lds((__attribute__((address_space(1))) void*)(g),
                                   (__attribute__((address_space(3))) void*)(lds_base),
                                   16, 0, 0);
#else
  *(bf16x8*)(lds_base + lane * 8) = *(const bf16x8*)g;
#endif
}

// XOR-swizzled LDS index for a 64-col bf16 tile (8 chunks of 8 shorts per row)
__device__ inline int swz(int row, int chunk) {
  return row * 64 + (((chunk ^ (row & 7)) & 7) << 3);
}

// ---------- pack kernels ----------
__global__ void cvt_x_split(const float* __restrict__ x,
                            unsigned short* __restrict__ xh, unsigned short* __restrict__ xl) {
  int i = (blockIdx.x * 256 + threadIdx.x) * 8;
  bf16x8 oh, ol;
  #pragma unroll
  for (int j = 0; j < 8; ++j) {
    unsigned short hi, lo;
    split_bf16(x[i + j], hi, lo);
    oh[j] = (short)hi; ol[j] = (short)lo;
  }
  *(bf16x8*)(xh + i) = oh;
  *(bf16x8*)(xl + i) = ol;
}

// WcatT[c'][m] split, c' = p*1024 + h*64 + k  (p: 0=Q,1=K,2=V), from W_p[h][m][k]
__global__ void pack_qkv_split(const float* __restrict__ Wq, const float* __restrict__ Wk,
                               const float* __restrict__ Wv,
                               unsigned short* __restrict__ Wh, unsigned short* __restrict__ Wl) {
  __shared__ float tile[64][65];
  int bid = blockIdx.x;               // p*256 + h*16 + mt
  int p = bid >> 8, h = (bid >> 4) & 15, mt = bid & 15;
  const float* W = (p == 0) ? Wq : (p == 1) ? Wk : Wv;
  const float* src = W + (size_t)h * (DM * DKV);
  int t = threadIdx.x;
  int m0 = mt * 64;
  #pragma unroll
  for (int pass = 0; pass < 16; ++pass) {
    int row = pass * 4 + (t >> 6), col = t & 63;
    tile[row][col] = src[(size_t)(m0 + row) * DKV + col];
  }
  __syncthreads();
  int cbase = p * 1024 + h * 64;
  #pragma unroll
  for (int pass = 0; pass < 16; ++pass) {
    int krow = pass * 4 + (t >> 6), mcol = t & 63;
    unsigned short hi, lo;
    split_bf16(tile[mcol][krow], hi, lo);
    size_t idx = (size_t)(cbase + krow) * DM + m0 + mcol;
    Wh[idx] = hi; Wl[idx] = lo;
  }
}

// WoT[mo][c] = Wo[c][mo], single bf16
__global__ void pack_wo(const float* __restrict__ Wo, unsigned short* __restrict__ WoT) {
  __shared__ float tile[64][65];
  int ib = blockIdx.x >> 4, jb = blockIdx.x & 15;
  int t = threadIdx.x;
  #pragma unroll
  for (int pass = 0; pass < 16; ++pass) {
    int row = pass * 4 + (t >> 6), col = t & 63;
    tile[row][col] = Wo[(size_t)(ib * 64 + row) * DM + jb * 64 + col];
  }
  __syncthreads();
  #pragma unroll
  for (int pass = 0; pass < 16; ++pass) {
    int a = pass * 4 + (t >> 6), b = t & 63;
    WoT[(size_t)(jb * 64 + a) * DM + ib * 64 + b] = bf16_rtn(tile[b][a]);
  }
}

// ---------- gemm_qk: split-precision x@Wqk^T, tile 128x128, BK=64, swizzled ----------
// LDS tiles are 64-col XOR-swizzled (same scheme as flash): staged via
// global_load_lds with pre-swizzled SOURCE chunk (c8^r8, an involution),
// read back with the swizzled chunk -> every ds_read_b128 hits all 32 banks
// uniformly (8 dwords/bank, the b128 minimum).  BK=64 halves barrier count.
// grid dim3(16=bn, 32=bm): bn%8 -> weight tiles pinned per XCD.
__global__ __launch_bounds__(256, 2)
void gemm_qk(const unsigned short* __restrict__ Ah, const unsigned short* __restrict__ Al,
             const unsigned short* __restrict__ Bh, const unsigned short* __restrict__ Bl,
             unsigned short* __restrict__ Qh, unsigned short* __restrict__ Ql,
             unsigned short* __restrict__ Kh, unsigned short* __restrict__ Kl) {
  __shared__ unsigned short AsH[128 * 64], AsL[128 * 64];   // 16 KB each
  __shared__ unsigned short BsH[128 * 64], BsL[128 * 64];   // total 64 KB
  const int tid = threadIdx.x;
  const int w = tid >> 6, lane = tid & 63;
  const int quad = lane >> 4, l16 = lane & 15;
  const int wm = w >> 1, wn = w & 1;
  const int bn = blockIdx.x, bm = blockIdx.y;

  f32x4 acc[4][4];
  #pragma unroll
  for (int i = 0; i < 4; ++i)
    #pragma unroll
    for (int j = 0; j < 4; ++j) acc[i][j] = (f32x4){0.f, 0.f, 0.f, 0.f};

  // staging: wave w -> rows [w*32, w*32+32), 4 passes of 8 rows; lane: row += lane>>3,
  // source chunk = (lane&7) ^ (lane>>3)  (involution of the read-side swizzle)
  const int r8 = lane >> 3, c8 = lane & 7;
  const int cs = c8 ^ r8;
  const size_t offA = (size_t)(bm * 128 + w * 32 + r8) * DM + cs * 8;
  const size_t offB = (size_t)(bn * 128 + w * 32 + r8) * DM + cs * 8;

  for (int kk = 0; kk < DM / 64; ++kk) {
    #pragma unroll
    for (int ps = 0; ps < 4; ++ps) {
      unsigned short* dA = AsH + (w * 32 + ps * 8) * 64;
      unsigned short* dAl = AsL + (w * 32 + ps * 8) * 64;
      unsigned short* dB = BsH + (w * 32 + ps * 8) * 64;
      unsigned short* dBl = BsL + (w * 32 + ps * 8) * 64;
      stage16(Ah + offA + kk * 64 + ps * 8 * DM, dA,  lane);
      stage16(Al + offA + kk * 64 + ps * 8 * DM, dAl, lane);
      stage16(Bh + offB + kk * 64 + ps * 8 * DM, dB,  lane);
      stage16(Bl + offB + kk * 64 + ps * 8 * DM, dBl, lane);
    }
    asm volatile("s_waitcnt vmcnt(0)" ::: "memory");
    __syncthreads();
    #pragma unroll
    for (int ks = 0; ks < 2; ++ks) {
      bf16x8 afh[4], afl[4], bfh[4], bfl[4];
      #pragma unroll
      for (int mt = 0; mt < 4; ++mt) {
        int row = wm * 64 + mt * 16 + l16;
        int ad = row * 64 + ((((ks * 4 + quad) ^ (row & 7)) & 7) << 3);
        afh[mt] = *(const bf16x8*)(AsH + ad);
        afl[mt] = *(const bf16x8*)(AsL + ad);
      }
      #pragma unroll
      for (int nt = 0; nt < 4; ++nt) {
        int row = wn * 64 + nt * 16 + l16;
        int ad = row * 64 + ((((ks * 4 + quad) ^ (row & 7)) & 7) << 3);
        bfh[nt] = *(const bf16x8*)(BsH + ad);
        bfl[nt] = *(const bf16x8*)(BsL + ad);
      }
      #pragma unroll
      for (int mt = 0; mt < 4; ++mt)
        #pragma unroll
        for (int nt = 0; nt < 4; ++nt) {
          acc[mt][nt] = __builtin_amdgcn_mfma_f32_16x16x32_bf16(afh[mt], bfh[nt], acc[mt][nt], 0, 0, 0);
          acc[mt][nt] = __builtin_amdgcn_mfma_f32_16x16x32_bf16(afh[mt], bfl[nt], acc[mt][nt], 0, 0, 0);
          acc[mt][nt] = __builtin_amdgcn_mfma_f32_16x16x32_bf16(afl[mt], bfh[nt], acc[mt][nt], 0, 0, 0);
        }
    }
    __syncthreads();
  }

  const float SCL = 0.18033688011112042f;  // (1/sqrt(64)) * log2(e), folded into Q
  #pragma unroll
  for (int mt = 0; mt < 4; ++mt) {
    int m_g = bm * 128 + wm * 64 + mt * 16 + quad * 4;
    #pragma unroll
    for (int nt = 0; nt < 4; ++nt) {
      int n_g = bn * 128 + wn * 64 + nt * 16 + l16;
      int p = n_g >> 10, h = (n_g >> 6) & 15, k = n_g & 63;
      #pragma unroll
      for (int r = 0; r < 4; ++r) {
        int row = m_g + r;
        int b = row >> 11, s = row & 2047;
        int bh = b * HEADS + h;
        float v = acc[mt][nt][r];
        size_t idx = ((size_t)(bh * SEQ + s)) * DKV + k;
        unsigned short hi, lo;
        if (p == 0) {
          split_bf16(v * SCL, hi, lo);
          Qh[idx] = hi; Ql[idx] = lo;
        } else {
          split_bf16(v, hi, lo);
          Kh[idx] = hi; Kl[idx] = lo;
        }
      }
    }
  }
}

// ---------- gemm_v: plain bf16 x@Wv^T -> Vt transposed ----------
// tile 64(M)x128(N), BK=64, swizzled LDS. grid dim3(8=bn, 64=bm) = 512 blocks
// -> 2 blocks/CU (was 1 at 128x128).
__global__ __launch_bounds__(256, 2)
void gemm_v(const unsigned short* __restrict__ A, const unsigned short* __restrict__ Bt,
            unsigned short* __restrict__ Vt) {
  __shared__ unsigned short As[64 * 64];     // 8 KB
  __shared__ unsigned short Bs[128 * 64];    // 16 KB
  const int tid = threadIdx.x;
  const int w = tid >> 6, lane = tid & 63;
  const int quad = lane >> 4, l16 = lane & 15;
  const int wm = w >> 1, wn = w & 1;
  const int bn = blockIdx.x, bm = blockIdx.y;

  f32x4 acc[2][4];
  #pragma unroll
  for (int i = 0; i < 2; ++i)
    #pragma unroll
    for (int j = 0; j < 4; ++j) acc[i][j] = (f32x4){0.f, 0.f, 0.f, 0.f};

  const int r8 = lane >> 3, c8 = lane & 7;
  const int cs = c8 ^ r8;
  const size_t offA = (size_t)(bm * 64 + w * 16 + r8) * DM + cs * 8;   // 16 A-rows/wave
  const size_t offB = (size_t)(bn * 128 + w * 32 + r8) * DM + cs * 8;  // 32 B-rows/wave

  for (int kk = 0; kk < DM / 64; ++kk) {
    #pragma unroll
    for (int ps = 0; ps < 2; ++ps)
      stage16(A + offA + kk * 64 + ps * 8 * DM, As + (w * 16 + ps * 8) * 64, lane);
    #pragma unroll
    for (int ps = 0; ps < 4; ++ps)
      stage16(Bt + offB + kk * 64 + ps * 8 * DM, Bs + (w * 32 + ps * 8) * 64, lane);
    asm volatile("s_waitcnt vmcnt(0)" ::: "memory");
    __syncthreads();
    #pragma unroll
    for (int ks = 0; ks < 2; ++ks) {
      bf16x8 af[2], bfr[4];
      #pragma unroll
      for (int mt = 0; mt < 2; ++mt) {
        int row = wm * 32 + mt * 16 + l16;
        af[mt] = *(const bf16x8*)(As + row * 64 + ((((ks * 4 + quad) ^ (row & 7)) & 7) << 3));
      }
      #pragma unroll
      for (int nt = 0; nt < 4; ++nt) {
        int row = wn * 64 + nt * 16 + l16;
        bfr[nt] = *(const bf16x8*)(Bs + row * 64 + ((((ks * 4 + quad) ^ (row & 7)) & 7) << 3));
      }
      #pragma unroll
      for (int mt = 0; mt < 2; ++mt)
        #pragma unroll
        for (int nt = 0; nt < 4; ++nt)
          acc[mt][nt] = __builtin_amdgcn_mfma_f32_16x16x32_bf16(af[mt], bfr[nt], acc[mt][nt], 0, 0, 0);
    }
    __syncthreads();
  }

  #pragma unroll
  for (int mt = 0; mt < 2; ++mt) {
    int m_g = bm * 64 + wm * 32 + mt * 16 + quad * 4;
    #pragma unroll
    for (int nt = 0; nt < 4; ++nt) {
      int n_g = bn * 128 + wn * 64 + nt * 16 + l16;   // 0..1023 within V block
      int h = n_g >> 6, k = n_g & 63;
      #pragma unroll
      for (int r = 0; r < 4; ++r) {
        int row = m_g + r;
        int b = row >> 11, s = row & 2047;
        int bh = b * HEADS + h;
        Vt[((size_t)(bh * DKV + k)) * SEQ + s] = bf16_rtn(acc[mt][nt][r]);
      }
    }
  }
}

// ---------- flash: S^T = K.Q^T (split), P^T C-layout == K=16 B-layout ----------
// q-block = 128 rows (32 q-rows per wave, qt=2) — best K-fragment amortization.
// Staging: global_load_lds DMA into DOUBLE-BUFFERED swizzled LDS (pre-swizzled
// global source, linear LDS dest), one barrier per kt-iteration.
// s_setprio(1) around MFMA clusters (T5): the two independent blocks/CU sit at
// different phases, so the scheduler can prefer the MFMA-issuing wave.
// grid dim3(32=bh, 16=qb); id%8 -> head's K/V pinned per XCD.
__global__ __launch_bounds__(256, 2)
void flash(const unsigned short* __restrict__ Qh, const unsigned short* __restrict__ Ql,
           const unsigned short* __restrict__ Kh, const unsigned short* __restrict__ Kl,
           const unsigned short* __restrict__ Vt, unsigned short* __restrict__ ctx) {
  __shared__ unsigned short KtH[2][64 * 64], KtL[2][64 * 64], Vts[2][64 * 64];
  const int tid = threadIdx.x;
  const int w = tid >> 6, lane = tid & 63, quad = lane >> 4, l16 = lane & 15;
  const int bh = blockIdx.x;
  const int q0 = blockIdx.y * 128;

  // Q B-frags (scaled by SCL already): [n=q][k=d], split hi/lo
  bf16x8 qfh[2][2], qfl[2][2];
  #pragma unroll
  for (int qt = 0; qt < 2; ++qt) {
    int qrow = q0 + w * 32 + qt * 16 + l16;
    size_t base = ((size_t)(bh * SEQ + qrow)) * DKV + quad * 8;
    qfh[qt][0] = *(const bf16x8*)(Qh + base);
    qfh[qt][1] = *(const bf16x8*)(Qh + base + 32);
    qfl[qt][0] = *(const bf16x8*)(Ql + base);
    qfl[qt][1] = *(const bf16x8*)(Ql + base + 32);
  }

  float m_run[2] = {-1e30f, -1e30f};
  float l_run[2] = {0.f, 0.f};
  f32x4 acc[2][4];
  #pragma unroll
  for (int qt = 0; qt < 2; ++qt)
    #pragma unroll
    for (int vt = 0; vt < 4; ++vt) acc[qt][vt] = (f32x4){0.f, 0.f, 0.f, 0.f};

  // staging geometry: wave w stages rows [w*16, w*16+16) of each tile, 2 passes
  // of 8 rows (1 KB per global_load_lds).  lane -> row = base + (lane>>3),
  // source chunk csrc = (lane&7) ^ (lane>>3)  (== (lane&7) ^ (row&7)).
  const int srow = w * 16 + (lane >> 3);
  const int csrc = (lane & 7) ^ (lane >> 3);
  const unsigned short* kh_src = Kh + ((size_t)(bh * SEQ) + srow) * DKV + csrc * 8;
  const unsigned short* kl_src = Kl + ((size_t)(bh * SEQ) + srow) * DKV + csrc * 8;
  const unsigned short* v_src  = Vt + ((size_t)(bh * DKV) + srow) * SEQ + csrc * 8;

  #define STAGE(buf, kt0)                                                     \
    do {                                                                      \
      unsigned short* dH = &KtH[buf][(w * 16) * 64];                          \
      unsigned short* dL = &KtL[buf][(w * 16) * 64];                          \
      unsigned short* dV = &Vts[buf][(w * 16) * 64];                          \
      stage16(kh_src + (size_t)(kt0) * DKV,            dH,       lane);       \
      stage16(kh_src + (size_t)(kt0) * DKV + 8 * DKV,  dH + 512, lane);       \
      stage16(kl_src + (size_t)(kt0) * DKV,            dL,       lane);       \
      stage16(kl_src + (size_t)(kt0) * DKV + 8 * DKV,  dL + 512, lane);       \
      stage16(v_src  + (kt0),                          dV,       lane);       \
      stage16(v_src  + (kt0) + 8 * SEQ,                dV + 512, lane);       \
    } while (0)

  STAGE(0, 0);
  asm volatile("s_waitcnt vmcnt(0)" ::: "memory");
  __syncthreads();
  int cur = 0;

  for (int kt = 0; kt < SEQ / 64; ++kt) {
    // issue next tile's DMA early; it flies under this iteration's compute
    if (kt + 1 < SEQ / 64) STAGE(cur ^ 1, (kt + 1) * 64);

    const unsigned short* kH = KtH[cur];
    const unsigned short* kL = KtL[cur];
    const unsigned short* vS = Vts[cur];

    // S^T[key][q] = Kh.Qh + Kh.Ql + Kl.Qh
    f32x4 st[4][2];
    __builtin_amdgcn_s_setprio(1);
    #pragma unroll
    for (int mt = 0; mt < 4; ++mt) {
      int rowA = mt * 16 + l16;
      bf16x8 kah0 = *(const bf16x8*)(kH + swz(rowA, quad));
      bf16x8 kah1 = *(const bf16x8*)(kH + swz(rowA, quad + 4));
      bf16x8 kal0 = *(const bf16x8*)(kL + swz(rowA, quad));
      bf16x8 kal1 = *(const bf16x8*)(kL + swz(rowA, quad + 4));
      #pragma unroll
      for (int qt = 0; qt < 2; ++qt) {
        f32x4 c = (f32x4){0.f, 0.f, 0.f, 0.f};
        c = __builtin_amdgcn_mfma_f32_16x16x32_bf16(kah0, qfh[qt][0], c, 0, 0, 0);
        c = __builtin_amdgcn_mfma_f32_16x16x32_bf16(kah1, qfh[qt][1], c, 0, 0, 0);
        c = __builtin_amdgcn_mfma_f32_16x16x32_bf16(kah0, qfl[qt][0], c, 0, 0, 0);
        c = __builtin_amdgcn_mfma_f32_16x16x32_bf16(kah1, qfl[qt][1], c, 0, 0, 0);
        c = __builtin_amdgcn_mfma_f32_16x16x32_bf16(kal0, qfh[qt][0], c, 0, 0, 0);
        c = __builtin_amdgcn_mfma_f32_16x16x32_bf16(kal1, qfh[qt][1], c, 0, 0, 0);
        st[mt][qt] = c;
      }
    }
    __builtin_amdgcn_s_setprio(0);

    // online softmax per q-column (lane&15); vote-skip rescale when max unchanged
    bf16x4 pb[2][4];
    #pragma unroll
    for (int qt = 0; qt < 2; ++qt) {
      float cm = -1e30f;
      #pragma unroll
      for (int mt = 0; mt < 4; ++mt)
        #pragma unroll
        for (int r = 0; r < 4; ++r) cm = fmaxf(cm, st[mt][qt][r]);
      cm = fmaxf(cm, __shfl_xor(cm, 16));
      cm = fmaxf(cm, __shfl_xor(cm, 32));
      bool upd = cm > m_run[qt];
      float mn = upd ? cm : m_run[qt];
      float ssum = 0.f;
      #pragma unroll
      for (int mt = 0; mt < 4; ++mt) {
        float p0 = fast_exp2(st[mt][qt][0] - mn);
        float p1 = fast_exp2(st[mt][qt][1] - mn);
        float p2 = fast_exp2(st[mt][qt][2] - mn);
        float p3 = fast_exp2(st[mt][qt][3] - mn);
        ssum += (p0 + p1) + (p2 + p3);
        union { bf16x4 v; unsigned u2[2]; } pk;
        pk.u2[0] = pack2_bf16(p0, p1);
        pk.u2[1] = pack2_bf16(p2, p3);
        pb[qt][mt] = pk.v;
      }
      ssum += __shfl_xor(ssum, 16);
      ssum += __shfl_xor(ssum, 32);
      if (__ballot(upd)) {
        float alpha = fast_exp2(m_run[qt] - mn);
        m_run[qt] = mn;
        l_run[qt] = l_run[qt] * alpha + ssum;
        #pragma unroll
        for (int vt = 0; vt < 4; ++vt) acc[qt][vt] = acc[qt][vt] * alpha;
      } else {
        l_run[qt] += ssum;
      }
    }

    // O^T[v][q] += Vt-tile[m=v][k=key] . P^T[k=key][n=q]  (K=16, B direct from regs)
    __builtin_amdgcn_s_setprio(1);
    #pragma unroll
    for (int vt = 0; vt < 4; ++vt) {
      #pragma unroll
      for (int mt = 0; mt < 4; ++mt) {
        int row = vt * 16 + l16;
        int addr = row * 64 + ((((mt * 2 + (quad >> 1)) ^ (row & 7)) & 7) << 3) + (quad & 1) * 4;
        bf16x4 va = *(const bf16x4*)(vS + addr);
        #pragma unroll
        for (int qt = 0; qt < 2; ++qt)
          acc[qt][vt] = mfma16x16x16_bf16(va, pb[qt][mt], acc[qt][vt]);
      }
    }
    __builtin_amdgcn_s_setprio(0);

    // drain this wave's next-tile DMA, then one barrier: all waves done reading
    // buf[cur] AND all staged writes to buf[cur^1] visible
    asm volatile("s_waitcnt vmcnt(0)" ::: "memory");
    __syncthreads();
    cur ^= 1;
  }
  #undef STAGE

  // epilogue: ctx[bs][h*64 + v] bf16 (perm-packed 8B stores)
  int h = bh & 15, b = bh >> 4;
  #pragma unroll
  for (int qt = 0; qt < 2; ++qt) {
    float inv = 1.0f / l_run[qt];
    int bs = b * SEQ + q0 + w * 32 + qt * 16 + l16;
    #pragma unroll
    for (int vt = 0; vt < 4; ++vt) {
      union { bf16x4 v; unsigned u2[2]; } pk;
      pk.u2[0] = pack2_bf16(acc[qt][vt][0] * inv, acc[qt][vt][1] * inv);
      pk.u2[1] = pack2_bf16(acc[qt][vt][2] * inv, acc[qt][vt][3] * inv);
      *(bf16x4*)(ctx + (size_t)bs * DM + h * 64 + vt * 16 + quad * 4) = pk.v;
    }
  }
}

// ---------- GEMM2: ctx @ WoT^T -> fp32 out ----------
// tile 64(M)x128(N), BK=64, swizzled LDS. grid dim3(8=bn, 64=bm) = 512 blocks.
__global__ __launch_bounds__(256, 2)
void gemm_out(const unsigned short* __restrict__ A, const unsigned short* __restrict__ Bt,
              float* __restrict__ out) {
  __shared__ unsigned short As[64 * 64];     // 8 KB
  __shared__ unsigned short Bs[128 * 64];    // 16 KB
  const int tid = threadIdx.x;
  const int w = tid >> 6, lane = tid & 63;
  const int quad = lane >> 4, l16 = lane & 15;
  const int wm = w >> 1, wn = w & 1;
  const int bn = blockIdx.x, bm = blockIdx.y;

  f32x4 acc[2][4];
  #pragma unroll
  for (int i = 0; i < 2; ++i)
    #pragma unroll
    for (int j = 0; j < 4; ++j) acc[i][j] = (f32x4){0.f, 0.f, 0.f, 0.f};

  const int r8 = lane >> 3, c8 = lane & 7;
  const int cs = c8 ^ r8;
  const size_t offA = (size_t)(bm * 64 + w * 16 + r8) * DM + cs * 8;
  const size_t offB = (size_t)(bn * 128 + w * 32 + r8) * DM + cs * 8;

  for (int kk = 0; kk < DM / 64; ++kk) {
    #pragma unroll
    for (int ps = 0; ps < 2; ++ps)
      stage16(A + offA + kk * 64 + ps * 8 * DM, As + (w * 16 + ps * 8) * 64, lane);
    #pragma unroll
    for (int ps = 0; ps < 4; ++ps)
      stage16(Bt + offB + kk * 64 + ps * 8 * DM, Bs + (w * 32 + ps * 8) * 64, lane);
    asm volatile("s_waitcnt vmcnt(0)" ::: "memory");
    __syncthreads();
    #pragma unroll
    for (int ks = 0; ks < 2; ++ks) {
      bf16x8 af[2], bfr[4];
      #pragma unroll
      for (int mt = 0; mt < 2; ++mt) {
        int row = wm * 32 + mt * 16 + l16;
        af[mt] = *(const bf16x8*)(As + row * 64 + ((((ks * 4 + quad) ^ (row & 7)) & 7) << 3));
      }
      #pragma unroll
      for (int nt = 0; nt < 4; ++nt) {
        int row = wn * 64 + nt * 16 + l16;
        bfr[nt] = *(const bf16x8*)(Bs + row * 64 + ((((ks * 4 + quad) ^ (row & 7)) & 7) << 3));
      }
      #pragma unroll
      for (int mt = 0; mt < 2; ++mt)
        #pragma unroll
        for (int nt = 0; nt < 4; ++nt)
          acc[mt][nt] = __builtin_amdgcn_mfma_f32_16x16x32_bf16(af[mt], bfr[nt], acc[mt][nt], 0, 0, 0);
    }
    __syncthreads();
  }

  #pragma unroll
  for (int mt = 0; mt < 2; ++mt) {
    int m_g = bm * 64 + wm * 32 + mt * 16 + quad * 4;
    #pragma unroll
    for (int nt = 0; nt < 4; ++nt) {
      int n_g = bn * 128 + wn * 64 + nt * 16 + l16;
      #pragma unroll
      for (int r = 0; r < 4; ++r)
        out[(size_t)(m_g + r) * DM + n_g] = acc[mt][nt][r];
    }
  }
}

// ---------- launch ----------
extern "C" void kernel_launch(void* const* d_in, const int* in_sizes, int n_in,
                              void* d_out, int out_size, void* d_ws, size_t ws_size,
                              hipStream_t stream) {
  const float* x  = (const float*)d_in[0];
  const float* Wk = (const float*)d_in[1];
  const float* Wq = (const float*)d_in[2];
  const float* Wv = (const float*)d_in[3];
  const float* Wo = (const float*)d_in[4];
  float* out = (float*)d_out;

  unsigned short* xh  = (unsigned short*)d_ws;                  // [4096][1024]
  unsigned short* xl  = xh  + (size_t)BS * DM;
  unsigned short* Wh  = xl  + (size_t)BS * DM;                  // [3072][1024]
  unsigned short* Wl  = Wh  + (size_t)3 * DM * DM;
  unsigned short* WoT = Wl  + (size_t)3 * DM * DM;              // [1024][1024]
  unsigned short* Qh  = WoT + (size_t)DM * DM;                  // [32][2048][64]
  unsigned short* Ql  = Qh  + (size_t)BHD * SEQ * DKV;
  unsigned short* Kh  = Ql  + (size_t)BHD * SEQ * DKV;
  unsigned short* Kl  = Kh  + (size_t)BHD * SEQ * DKV;
  unsigned short* Vtb = Kl  + (size_t)BHD * SEQ * DKV;          // [32][64][2048]
  unsigned short* ctx = Vtb + (size_t)BHD * SEQ * DKV;          // [4096][1024]

  cvt_x_split<<<(BS * DM) / (256 * 8), 256, 0, stream>>>(x, xh, xl);
  pack_qkv_split<<<3 * 16 * 16, 256, 0, stream>>>(Wq, Wk, Wv, Wh, Wl);
  pack_wo<<<16 * 16, 256, 0, stream>>>(Wo, WoT);
  gemm_qk<<<dim3(16, 32), 256, 0, stream>>>(xh, xl, Wh, Wl, Qh, Ql, Kh, Kl);
  gemm_v<<<dim3(8, 64), 256, 0, stream>>>(xh, Wh + (size_t)2048 * DM, Vtb);
  flash<<<dim3(BHD, SEQ / 128), 256, 0, stream>>>(Qh, Ql, Kh, Kl, Vtb, ctx);
  gemm_out<<<dim3(8, 64), 256, 0, stream>>>(ctx, WoT, out);
}